// Round 13
// baseline (361.426 us; speedup 1.0000x reference)
//
#include <hip/hip_runtime.h>
#include <hip/hip_bf16.h>
#include <hip/hip_fp16.h>
#include <math.h>

#define BATCH 4096
#define INPUT_SIZE 256
#define LATENT 64
#define HIDDEN 512
#define ACTIONS 12
#define EXPERTS 8
#define GATE_H 128
#define IN_DIM (INPUT_SIZE + LATENT)   // 320
#define INTER (HIDDEN + LATENT)        // 576

typedef unsigned int u32;
typedef unsigned short u16;
typedef __attribute__((ext_vector_type(8))) short short8;
typedef __attribute__((ext_vector_type(8))) _Float16 f16x8;
typedef __attribute__((ext_vector_type(16))) float f32x16;

__device__ __forceinline__ u16 f2h(float x) { return __half_as_ushort(__float2half(x)); }
__device__ __forceinline__ float h2f(u16 u) { return __half2float(__ushort_as_half(u)); }

__device__ __forceinline__ void gload16(const void* g, void* lds) {
    __builtin_amdgcn_global_load_lds(
        (const __attribute__((address_space(1))) u32*)g,
        (__attribute__((address_space(3))) u32*)lds, 16, 0, 0);
}

// ---------------------------------------------------------------------------
// Gate MLP v4 (verified r8): 4 samples/block, 1024 blocks, 256 threads =
// (64 neuron-pairs x 4 K-quarters), float2 loads, LDS 4-way reduce.
// ---------------------------------------------------------------------------
#define GS 4
__global__ __launch_bounds__(256) void gate_forward_v4(
    const float* __restrict__ z, const float* __restrict__ c,
    const float* __restrict__ W0t, const float* __restrict__ b0,
    const float* __restrict__ W1t, const float* __restrict__ b1,
    const float* __restrict__ W2t, const float* __restrict__ b2,
    float* __restrict__ coeff) {
    __shared__ float xs[GS][IN_DIM + 2];
    __shared__ float hq[4][GS][GATE_H];
    __shared__ float h1[GS][GATE_H + 1];
    __shared__ float h2[GS][GATE_H + 1];
    __shared__ float red[GS][EXPERTS];

    const int b4 = blockIdx.x * GS;
    const int t = threadIdx.x;
    const int np = t & 63, kq = t >> 6;
    const int n0 = np * 2;

    for (int idx = t; idx < GS * IN_DIM; idx += 256) {
        const int s = idx / IN_DIM, i = idx - s * IN_DIM;
        xs[s][i] = (i < LATENT) ? z[(size_t)(b4 + s) * LATENT + i]
                                : c[(size_t)(b4 + s) * INPUT_SIZE + (i - LATENT)];
    }
    __syncthreads();

    {
        float a0[GS], a1[GS];
        #pragma unroll
        for (int s = 0; s < GS; ++s) { a0[s] = 0.f; a1[s] = 0.f; }
        const int i0 = kq * 80;
        #pragma unroll 8
        for (int i = i0; i < i0 + 80; ++i) {
            const float2 wv2 = *(const float2*)(W0t + (size_t)i * GATE_H + n0);
            #pragma unroll
            for (int s = 0; s < GS; ++s) {
                a0[s] = fmaf(xs[s][i], wv2.x, a0[s]);
                a1[s] = fmaf(xs[s][i], wv2.y, a1[s]);
            }
        }
        #pragma unroll
        for (int s = 0; s < GS; ++s) { hq[kq][s][n0] = a0[s]; hq[kq][s][n0 + 1] = a1[s]; }
    }
    __syncthreads();
    if (kq == 0) {
        #pragma unroll
        for (int s = 0; s < GS; ++s)
            #pragma unroll
            for (int j = 0; j < 2; ++j) {
                const int n = n0 + j;
                const float v = b0[n] + hq[0][s][n] + hq[1][s][n] + hq[2][s][n] + hq[3][s][n];
                h1[s][n] = v > 0.f ? v : expm1f(v);
            }
    }
    __syncthreads();

    {
        float a0[GS], a1[GS];
        #pragma unroll
        for (int s = 0; s < GS; ++s) { a0[s] = 0.f; a1[s] = 0.f; }
        const int i0 = kq * 32;
        #pragma unroll 8
        for (int i = i0; i < i0 + 32; ++i) {
            const float2 wv2 = *(const float2*)(W1t + (size_t)i * GATE_H + n0);
            #pragma unroll
            for (int s = 0; s < GS; ++s) {
                a0[s] = fmaf(h1[s][i], wv2.x, a0[s]);
                a1[s] = fmaf(h1[s][i], wv2.y, a1[s]);
            }
        }
        #pragma unroll
        for (int s = 0; s < GS; ++s) { hq[kq][s][n0] = a0[s]; hq[kq][s][n0 + 1] = a1[s]; }
    }
    __syncthreads();
    if (kq == 0) {
        #pragma unroll
        for (int s = 0; s < GS; ++s)
            #pragma unroll
            for (int j = 0; j < 2; ++j) {
                const int n = n0 + j;
                const float v = b1[n] + hq[0][s][n] + hq[1][s][n] + hq[2][s][n] + hq[3][s][n];
                h2[s][n] = v > 0.f ? v : expm1f(v);
            }
    }
    __syncthreads();

    if (t < GS * EXPERTS) {
        const int s = t >> 3, e = t & 7;
        float acc = b2[e];
        #pragma unroll 8
        for (int i = 0; i < GATE_H; ++i)
            acc = fmaf(h2[s][i], W2t[(size_t)i * EXPERTS + e], acc);
        red[s][e] = acc;
    }
    __syncthreads();
    if (t < GS) {
        float m = red[t][0];
        #pragma unroll
        for (int i = 1; i < EXPERTS; ++i) m = fmaxf(m, red[t][i]);
        float e[EXPERTS];
        float sum = 0.f;
        #pragma unroll
        for (int i = 0; i < EXPERTS; ++i) { e[i] = expf(red[t][i] - m); sum += e[i]; }
        const float inv = 1.f / sum;
        #pragma unroll
        for (int i = 0; i < EXPERTS; ++i)
            coeff[(size_t)(b4 + t) * EXPERTS + i] = e[i] * inv;
    }
}

// ---------------------------------------------------------------------------
// pack_all v3: weight packing (y<33) + activation packing (33<=y<49) +
// Lipschitz gate-weight row scaling (49<=y<58) + counter zeroing (y==58).
// ---------------------------------------------------------------------------
__global__ __launch_bounds__(256) void pack_all_kernel(
    const float* __restrict__ w0, const float* __restrict__ w1,
    const float* __restrict__ w2,
    const float* __restrict__ z, const float* __restrict__ c,
    u16* __restrict__ Bpk0, u16* __restrict__ Bpk1, u16* __restrict__ Bpk2,
    u16* __restrict__ Apk0, u16* __restrict__ Apk1, u16* __restrict__ Apk2,
    const float* __restrict__ gw0, const float* __restrict__ gc0,
    const float* __restrict__ gw1, const float* __restrict__ gc1,
    const float* __restrict__ gw2, const float* __restrict__ gc2,
    float* __restrict__ gW0t, float* __restrict__ gW1t, float* __restrict__ gW2t,
    int* __restrict__ ctrs) {
    const int t = threadIdx.x, wv = t >> 6, l = t & 63;
    const int x = blockIdx.x, y = blockIdx.y;

    if (y < 33) {
        __shared__ float tile[4][16][33];
        const float* w; u16* Bpk; int IN, OUT, nblk;
        if (y < 16)      { w = w0; Bpk = Bpk0; IN = IN_DIM; OUT = HIDDEN;  nblk = y; }
        else if (y < 32) { w = w1; Bpk = Bpk1; IN = INTER;  OUT = HIDDEN;  nblk = y - 16; }
        else             { w = w2; Bpk = Bpk2; IN = INTER;  OUT = ACTIONS; nblk = 0; }
        const int NK = IN / 16;
        const int e = x, n0 = nblk * 32;
        const int col = l & 31, half = l >> 5;
        char* base = (char*)Bpk + ((size_t)(nblk * EXPERTS + e) * NK) * 1024;

        for (int jj = wv; jj < NK; jj += 4) {
            #pragma unroll
            for (int i = 0; i < 8; ++i) {
                const int r = i * 2 + half;
                float v = 0.f;
                if (n0 + col < OUT) v = w[((size_t)e * IN + jj * 16 + r) * OUT + n0 + col];
                tile[wv][r][col] = v;
            }
            short8 hh;
            #pragma unroll
            for (int i = 0; i < 8; ++i)
                hh[i] = (short)f2h(tile[wv][half * 8 + i][col]);
            *(short8*)(base + (size_t)jj * 1024 + l * 16) = hh;
        }
    } else if (y < 49) {
        constexpr int NK0 = 20, NK1 = 36;
        const int bblk = (y - 33) * 8 + x;
        const int r = l & 31, half = l >> 5;
        const int row = bblk * 32 + r;
        char* base0 = (char*)Apk0 + (size_t)bblk * NK0 * 1024;
        char* base1 = (char*)Apk1 + (size_t)bblk * NK1 * 1024;
        char* base2 = (char*)Apk2 + (size_t)bblk * NK1 * 1024;

        for (int jj = wv; jj < NK0; jj += 4) {
            const int k = jj * 16 + half * 8;
            const float* src = (k < LATENT) ? (z + (size_t)row * LATENT + k)
                                            : (c + (size_t)row * INPUT_SIZE + (k - LATENT));
            short8 hh;
            #pragma unroll
            for (int i = 0; i < 8; ++i) hh[i] = (short)f2h(src[i]);
            *(short8*)(base0 + (size_t)jj * 1024 + l * 16) = hh;
            if (jj < 4) {
                *(short8*)(base1 + (size_t)jj * 1024 + l * 16) = hh;
                *(short8*)(base2 + (size_t)jj * 1024 + l * 16) = hh;
            }
        }
    } else if (y < 58) {
        const int row_g = (y - 49) * 32 + x * 4 + wv;
        if (row_g < 264) {
            const float* W; const float* cc; float* Wt; int cols, rows, row;
            if (row_g < 128)      { W = gw0; cc = gc0; Wt = gW0t; cols = IN_DIM; rows = GATE_H; row = row_g; }
            else if (row_g < 256) { W = gw1; cc = gc1; Wt = gW1t; cols = GATE_H; rows = GATE_H; row = row_g - 128; }
            else                  { W = gw2; cc = gc2; Wt = gW2t; cols = GATE_H; rows = EXPERTS; row = row_g - 256; }
            const float* w = W + (size_t)row * cols;
            float s = 0.f;
            for (int i = l; i < cols; i += 64) s += fabsf(w[i]);
            #pragma unroll
            for (int off = 32; off > 0; off >>= 1) s += __shfl_down(s, off, 64);
            s = __shfl(s, 0, 64);
            const float cv = cc[0];
            const float lipc = (cv > 0.f) ? (cv + log1pf(expf(-cv))) : log1pf(expf(cv));
            const float scale = fminf(lipc / s, 1.0f);
            for (int i = l; i < cols; i += 64)
                Wt[(size_t)i * rows + row] = w[i] * scale;
        }
    } else {
        if (x == 0) for (int i = t; i < 544; i += 256) ctrs[i] = 0;
    }
}

// ---------------------------------------------------------------------------
// moe_gemm_rp: r11-verified main gemm (256 thr, 2x2 waves, 128x64 tile,
// EPB=2, split-K 4, counted vmcnt(12)) + fused last-block reduce:
// after partial store, ticket on ctr[bx*8+by]; the 4th block reduces its
// (128 rows x 64 cols) tile: sum 4 f16 partials + coeff-mixed bias + ELU,
// packs next-layer A chunks. Same math/order as verified reduce_pack.
// ---------------------------------------------------------------------------
template<int NK>
__global__ __launch_bounds__(256) void moe_gemm_rp(
    const u16* __restrict__ Apk, const u16* __restrict__ Bpk,
    const float* __restrict__ coeff, const float* __restrict__ bias,
    u16* __restrict__ P16, u16* __restrict__ ApkNext, int* __restrict__ ctr) {
    constexpr int TOT = NK / 4;
    constexpr int GX = 32, GY = 8, GZ = 4;

    __shared__ __align__(16) char As[3 * 16384];
    __shared__ float coeffT[2][128];
    __shared__ int tick;

    const int t = threadIdx.x, wv = t >> 6, l = t & 63;
    const int wr = wv & 1, wc = wv >> 1;

    const int fid = blockIdx.x + GX * (blockIdx.y + GY * blockIdx.z);
    const int xcd = fid & 7, idx = fid >> 3;
    const int bx = xcd * 4 + (idx % 4);
    const int yz = idx / 4;
    const int by = yz % GY, bz = yz / GY;

    const int b0 = bx * 128;
    const int bblk0 = bx * 4;
    const int nblkg = by * 2 + wc;
    const int part = bz;
    const int estart = part * 2;

    for (int i2 = t; i2 < 2 * 128; i2 += 256)
        coeffT[i2 >> 7][i2 & 127] =
            coeff[(size_t)(b0 + (i2 & 127)) * EXPERTS + estart + (i2 >> 7)];

    const char* Ab = (const char*)Apk;
    const char* Bbase[2];
    #pragma unroll
    for (int e = 0; e < 2; ++e)
        Bbase[e] = (const char*)Bpk +
                   ((size_t)(nblkg * EXPERTS + estart + e) * NK) * 1024 + l * 16;

    f32x16 accE[2][2];
    accE[0][0] = (f32x16)0.f; accE[0][1] = (f32x16)0.f;
    accE[1][0] = (f32x16)0.f; accE[1][1] = (f32x16)0.f;

    f16x8 breg[2][2][4];

    auto stageA = [&](int s) {
        char* dst = As + (s % 3) * 16384;
        #pragma unroll
        for (int q = 0; q < 4; ++q) {
            const int cf = wv * 4 + q, bb = cf >> 2, kq = cf & 3;
            gload16(Ab + ((size_t)(bblk0 + bb) * NK + s * 4 + kq) * 1024 + l * 16,
                    dst + cf * 1024 + l * 16);
        }
    };

    __syncthreads();

    stageA(0);
    #pragma unroll
    for (int e = 0; e < 2; ++e)
        #pragma unroll
        for (int q = 0; q < 4; ++q)
            breg[0][e][q] = *(const f16x8*)(Bbase[e] + (size_t)q * 1024);
    stageA(1);
    #pragma unroll
    for (int e = 0; e < 2; ++e)
        #pragma unroll
        for (int q = 0; q < 4; ++q)
            breg[1][e][q] = *(const f16x8*)(Bbase[e] + (size_t)(4 + q) * 1024);

    #pragma unroll
    for (int s = 0; s < TOT; ++s) {
        if (s == TOT - 1) asm volatile("s_waitcnt vmcnt(0)" ::: "memory");
        else              asm volatile("s_waitcnt vmcnt(12)" ::: "memory");
        __builtin_amdgcn_sched_barrier(0);
        __builtin_amdgcn_s_barrier();
        __builtin_amdgcn_sched_barrier(0);

        if (s + 2 < TOT) stageA(s + 2);

        const char* buf = As + (s % 3) * 16384;
        f16x8 af0[4], af1[4];
        #pragma unroll
        for (int j = 0; j < 4; ++j) {
            af0[j] = *(const f16x8*)(buf + ((wr * 2 + 0) * 4 + j) * 1024 + l * 16);
            af1[j] = *(const f16x8*)(buf + ((wr * 2 + 1) * 4 + j) * 1024 + l * 16);
        }
        #pragma unroll
        for (int e = 0; e < 2; ++e)
            #pragma unroll
            for (int j = 0; j < 4; ++j) {
                accE[e][0] = __builtin_amdgcn_mfma_f32_32x32x16_f16(af0[j], breg[s & 1][e][j], accE[e][0], 0, 0, 0);
                accE[e][1] = __builtin_amdgcn_mfma_f32_32x32x16_f16(af1[j], breg[s & 1][e][j], accE[e][1], 0, 0, 0);
            }
        if (s + 2 < TOT) {
            #pragma unroll
            for (int e = 0; e < 2; ++e)
                #pragma unroll
                for (int q = 0; q < 4; ++q)
                    breg[s & 1][e][q] = *(const f16x8*)(Bbase[e] + (size_t)((s + 2) * 4 + q) * 1024);
        }
    }

    // partial store (f16)
    const int ncol = nblkg * 32 + (l & 31);
    #pragma unroll
    for (int m = 0; m < 2; ++m) {
        #pragma unroll
        for (int g = 0; g < 16; ++g) {
            const int rloc = (g & 3) + 8 * (g >> 2) + 4 * (l >> 5);
            const int row = wr * 64 + m * 32 + rloc;
            float v = coeffT[0][row] * accE[0][m][g] + coeffT[1][row] * accE[1][m][g];
            P16[((size_t)part * BATCH + b0 + row) * HIDDEN + ncol] = f2h(v);
        }
    }

    // ---- last-block fused reduce (ticket) ----
    __threadfence();                // release: partials visible device-wide
    __syncthreads();
    if (t == 0) tick = atomicAdd(&ctr[bx * GY + by], 1);
    __syncthreads();
    if (tick != GZ - 1) return;
    __threadfence();                // acquire: other parts' stores visible

    float* coeffS = (float*)As;                 // [128][8]
    float* biasS  = (float*)As + 128 * 8;       // [8][64]
    for (int i = t; i < 128 * 8; i += 256)
        coeffS[i] = coeff[(size_t)(b0 + (i >> 3)) * 8 + (i & 7)];
    for (int i = t; i < 8 * 64; i += 256)
        biasS[i] = bias[(i >> 6) * HIDDEN + by * 64 + (i & 63)];
    __syncthreads();

    const int r = l & 31, half = l >> 5;
    const int bblk = bblk0 + wv;
    const int row = bblk * 32 + r;
    const int rl8 = (wv * 32 + r) * 8;
    char* basep = (char*)ApkNext + (size_t)bblk * 36 * 1024;
    #pragma unroll
    for (int jj2 = 0; jj2 < 4; ++jj2) {
        const int jj = by * 4 + jj2;            // h-ksub 0..31
        const int cb = jj * 16 + half * 8;      // col 0..511
        float v[8];
        #pragma unroll
        for (int i = 0; i < 8; ++i) v[i] = 0.f;
        #pragma unroll
        for (int p = 0; p < GZ; ++p) {
            const short8 q = *(const short8*)(P16 + ((size_t)p * BATCH + row) * HIDDEN + cb);
            #pragma unroll
            for (int i = 0; i < 8; ++i) v[i] += h2f((u16)q[i]);
        }
        const int cl = cb - by * 64;
        #pragma unroll
        for (int e = 0; e < EXPERTS; ++e) {
            const float cv = coeffS[rl8 + e];
            #pragma unroll
            for (int i = 0; i < 8; ++i) v[i] = fmaf(cv, biasS[e * 64 + cl + i], v[i]);
        }
        short8 hh;
        #pragma unroll
        for (int i = 0; i < 8; ++i) {
            const float hv = v[i] > 0.f ? v[i] : expm1f(v[i]);
            hh[i] = (short)f2h(hv);
        }
        *(short8*)(basep + (size_t)(4 + jj) * 1024 + l * 16) = hh;
    }
}

// ---------------------------------------------------------------------------
// moe_gemm_l2f: layer-2 gemm (128 thr, 128x32, EPB=1, split-K 8 experts,
// f32 partials) + fused last-block reduce_out (ticket of 8 on ctr[bx]).
// ---------------------------------------------------------------------------
__global__ __launch_bounds__(128) void moe_gemm_l2f(
    const u16* __restrict__ Apk, const u16* __restrict__ Bpk,
    const float* __restrict__ coeff, const float* __restrict__ b2,
    float* __restrict__ P32, float* __restrict__ out, int* __restrict__ ctr) {
    constexpr int NK = 36, TOT = 9, GX = 32, GZ = 8;

    __shared__ __align__(16) char As[3 * 16384];
    __shared__ float coeffT[128];
    __shared__ int tick;

    const int t = threadIdx.x, wv = t >> 6, l = t & 63;
    const int wr = wv & 1;

    const int fid = blockIdx.x + GX * blockIdx.z;
    const int xcd = fid & 7, idx = fid >> 3;
    const int bx = xcd * 4 + (idx % 4);
    const int part = idx / 4;

    const int b0 = bx * 128;
    const int bblk0 = bx * 4;

    for (int i2 = t; i2 < 128; i2 += 128)
        coeffT[i2] = coeff[(size_t)(b0 + i2) * EXPERTS + part];

    const char* Ab = (const char*)Apk;
    const char* Bb = (const char*)Bpk + ((size_t)part * NK) * 1024 + l * 16;

    f32x16 accE[2];
    accE[0] = (f32x16)0.f; accE[1] = (f32x16)0.f;

    f16x8 breg[2][4];

    auto stageA = [&](int s) {
        char* dst = As + (s % 3) * 16384;
        #pragma unroll
        for (int q = 0; q < 8; ++q) {
            const int cf = wv * 8 + q, bb = cf >> 2, kq = cf & 3;
            gload16(Ab + ((size_t)(bblk0 + bb) * NK + s * 4 + kq) * 1024 + l * 16,
                    dst + cf * 1024 + l * 16);
        }
    };
    auto bload = [&](int s, int set) {
        #pragma unroll
        for (int q = 0; q < 4; ++q)
            breg[set][q] = *(const f16x8*)(Bb + (size_t)(s * 4 + q) * 1024);
    };

    __syncthreads();
    stageA(0); bload(0, 0);
    stageA(1); bload(1, 1);

    #pragma unroll
    for (int s = 0; s < TOT; ++s) {
        if (s == TOT - 1) asm volatile("s_waitcnt vmcnt(0)" ::: "memory");
        else              asm volatile("s_waitcnt vmcnt(12)" ::: "memory");
        __builtin_amdgcn_sched_barrier(0);
        __builtin_amdgcn_s_barrier();
        __builtin_amdgcn_sched_barrier(0);

        if (s + 2 < TOT) stageA(s + 2);

        const char* buf = As + (s % 3) * 16384;
        f16x8 af0[4], af1[4];
        #pragma unroll
        for (int j = 0; j < 4; ++j) {
            af0[j] = *(const f16x8*)(buf + ((wr * 2 + 0) * 4 + j) * 1024 + l * 16);
            af1[j] = *(const f16x8*)(buf + ((wr * 2 + 1) * 4 + j) * 1024 + l * 16);
        }
        #pragma unroll
        for (int j = 0; j < 4; ++j) {
            accE[0] = __builtin_amdgcn_mfma_f32_32x32x16_f16(af0[j], breg[s & 1][j], accE[0], 0, 0, 0);
            accE[1] = __builtin_amdgcn_mfma_f32_32x32x16_f16(af1[j], breg[s & 1][j], accE[1], 0, 0, 0);
        }
        if (s + 2 < TOT) bload(s + 2, s & 1);
    }

    const int ncol = l & 31;
    #pragma unroll
    for (int m = 0; m < 2; ++m) {
        #pragma unroll
        for (int g = 0; g < 16; ++g) {
            const int rloc = (g & 3) + 8 * (g >> 2) + 4 * (l >> 5);
            const int row = wr * 64 + m * 32 + rloc;
            P32[((size_t)part * BATCH + b0 + row) * 32 + ncol] = coeffT[row] * accE[m][g];
        }
    }

    // ---- last-block fused reduce_out ----
    __threadfence();
    __syncthreads();
    if (t == 0) tick = atomicAdd(&ctr[bx], 1);
    __syncthreads();
    if (tick != GZ - 1) return;
    __threadfence();

    for (int i = t; i < 128 * ACTIONS; i += 128) {
        const int rloc = i / ACTIONS, n = i % ACTIONS;
        const int row = b0 + rloc;
        float s = 0.f;
        #pragma unroll
        for (int p = 0; p < 8; ++p) s += P32[((size_t)p * BATCH + row) * 32 + n];
        const float* cf = coeff + (size_t)row * 8;
        #pragma unroll
        for (int e = 0; e < 8; ++e) s = fmaf(cf[e], b2[e * ACTIONS + n], s);
        out[(size_t)row * ACTIONS + n] = s;
    }
}

// ---------------------------------------------------------------------------
extern "C" void kernel_launch(void* const* d_in, const int* in_sizes, int n_in,
                              void* d_out, int out_size, void* d_ws, size_t ws_size,
                              hipStream_t stream) {
    const float* z   = (const float*)d_in[0];
    const float* c   = (const float*)d_in[1];
    const float* w0  = (const float*)d_in[2];
    const float* b0  = (const float*)d_in[3];
    const float* w1  = (const float*)d_in[4];
    const float* b1  = (const float*)d_in[5];
    const float* w2  = (const float*)d_in[6];
    const float* b2  = (const float*)d_in[7];
    const float* gw0 = (const float*)d_in[8];
    const float* gb0 = (const float*)d_in[9];
    const float* gc0 = (const float*)d_in[10];
    const float* gw1 = (const float*)d_in[11];
    const float* gb1 = (const float*)d_in[12];
    const float* gc1 = (const float*)d_in[13];
    const float* gw2 = (const float*)d_in[14];
    const float* gb2 = (const float*)d_in[15];
    const float* gc2 = (const float*)d_in[16];
    float* out = (float*)d_out;

    char* p = (char*)d_ws;
    float* coeff = (float*)p;  p += (size_t)BATCH * EXPERTS * 4;
    float* gW0t  = (float*)p;  p += (size_t)GATE_H * IN_DIM * 4;
    float* gW1t  = (float*)p;  p += (size_t)GATE_H * GATE_H * 4;
    float* gW2t  = (float*)p;  p += (size_t)EXPERTS * GATE_H * 4;
    u16* Apk0 = (u16*)p;       p += (size_t)128 * 20 * 1024;
    u16* Apk1 = (u16*)p;       p += (size_t)128 * 36 * 1024;
    u16* Apk2 = (u16*)p;       p += (size_t)128 * 36 * 1024;
    u16* Bpk0 = (u16*)p;       p += (size_t)16 * 8 * 20 * 1024;
    u16* Bpk1 = (u16*)p;       p += (size_t)16 * 8 * 36 * 1024;
    u16* Bpk2 = (u16*)p;       p += (size_t)8 * 36 * 1024;
    u16* P16  = (u16*)p;       p += (size_t)4 * BATCH * HIDDEN * 2;   // 16 MB
    float* P32 = (float*)P16;  // L2 path reuses region as f32 (4 MB)
    int* ctrs = (int*)p;       p += 544 * 4;
    int* ctr0 = ctrs;          // 256: L0 (bx,by)
    int* ctr1 = ctrs + 256;    // 256: L1 (bx,by)
    int* ctr2 = ctrs + 512;    // 32:  L2 (bx)

    // fused packing + gate-weight scaling + counter zeroing
    pack_all_kernel<<<dim3(8, 59), 256, 0, stream>>>(
        w0, w1, w2, z, c, Bpk0, Bpk1, Bpk2, Apk0, Apk1, Apk2,
        gw0, gc0, gw1, gc1, gw2, gc2, gW0t, gW1t, gW2t, ctrs);

    // gate MLP
    gate_forward_v4<<<BATCH / GS, 256, 0, stream>>>(z, c, gW0t, gb0, gW1t, gb1,
                                                    gW2t, gb2, coeff);

    // layer 0: gemm + fused reduce_pack (writes Apk1 h-region)
    moe_gemm_rp<20><<<dim3(32, 8, 4), 256, 0, stream>>>(
        Apk0, Bpk0, coeff, b0, P16, Apk1, ctr0);

    // layer 1: gemm + fused reduce_pack (writes Apk2 h-region)
    moe_gemm_rp<36><<<dim3(32, 8, 4), 256, 0, stream>>>(
        Apk1, Bpk1, coeff, b1, P16, Apk2, ctr1);

    // layer 2: gemm + fused reduce_out (writes final out)
    moe_gemm_l2f<<<dim3(32, 1, 8), 128, 0, stream>>>(
        Apk2, Bpk2, coeff, b2, P32, out, ctr2);
}

// Round 14
// 115.858 us; speedup vs baseline: 3.1196x; 3.1196x over previous
//
#include <hip/hip_runtime.h>
#include <hip/hip_bf16.h>
#include <hip/hip_fp16.h>
#include <math.h>

#define BATCH 4096
#define INPUT_SIZE 256
#define LATENT 64
#define HIDDEN 512
#define ACTIONS 12
#define EXPERTS 8
#define GATE_H 128
#define IN_DIM (INPUT_SIZE + LATENT)   // 320
#define INTER (HIDDEN + LATENT)        // 576

typedef unsigned int u32;
typedef unsigned short u16;
typedef __attribute__((ext_vector_type(8))) short short8;
typedef __attribute__((ext_vector_type(8))) _Float16 f16x8;
typedef __attribute__((ext_vector_type(16))) float f32x16;

__device__ __forceinline__ u16 f2h(float x) { return __half_as_ushort(__float2half(x)); }
__device__ __forceinline__ float h2f(u16 u) { return __half2float(__ushort_as_half(u)); }

__device__ __forceinline__ void gload16(const void* g, void* lds) {
    __builtin_amdgcn_global_load_lds(
        (const __attribute__((address_space(1))) u32*)g,
        (__attribute__((address_space(3))) u32*)lds, 16, 0, 0);
}

// ---------------------------------------------------------------------------
// Gate MLP v4 (verified r8): 4 samples/block, 1024 blocks, 256 threads =
// (64 neuron-pairs x 4 K-quarters), float2 loads, LDS 4-way reduce.
// ---------------------------------------------------------------------------
#define GS 4
__global__ __launch_bounds__(256) void gate_forward_v4(
    const float* __restrict__ z, const float* __restrict__ c,
    const float* __restrict__ W0t, const float* __restrict__ b0,
    const float* __restrict__ W1t, const float* __restrict__ b1,
    const float* __restrict__ W2t, const float* __restrict__ b2,
    float* __restrict__ coeff) {
    __shared__ float xs[GS][IN_DIM + 2];
    __shared__ float hq[4][GS][GATE_H];
    __shared__ float h1[GS][GATE_H + 1];
    __shared__ float h2[GS][GATE_H + 1];
    __shared__ float red[GS][EXPERTS];

    const int b4 = blockIdx.x * GS;
    const int t = threadIdx.x;
    const int np = t & 63, kq = t >> 6;
    const int n0 = np * 2;

    for (int idx = t; idx < GS * IN_DIM; idx += 256) {
        const int s = idx / IN_DIM, i = idx - s * IN_DIM;
        xs[s][i] = (i < LATENT) ? z[(size_t)(b4 + s) * LATENT + i]
                                : c[(size_t)(b4 + s) * INPUT_SIZE + (i - LATENT)];
    }
    __syncthreads();

    {
        float a0[GS], a1[GS];
        #pragma unroll
        for (int s = 0; s < GS; ++s) { a0[s] = 0.f; a1[s] = 0.f; }
        const int i0 = kq * 80;
        #pragma unroll 8
        for (int i = i0; i < i0 + 80; ++i) {
            const float2 wv2 = *(const float2*)(W0t + (size_t)i * GATE_H + n0);
            #pragma unroll
            for (int s = 0; s < GS; ++s) {
                a0[s] = fmaf(xs[s][i], wv2.x, a0[s]);
                a1[s] = fmaf(xs[s][i], wv2.y, a1[s]);
            }
        }
        #pragma unroll
        for (int s = 0; s < GS; ++s) { hq[kq][s][n0] = a0[s]; hq[kq][s][n0 + 1] = a1[s]; }
    }
    __syncthreads();
    if (kq == 0) {
        #pragma unroll
        for (int s = 0; s < GS; ++s)
            #pragma unroll
            for (int j = 0; j < 2; ++j) {
                const int n = n0 + j;
                const float v = b0[n] + hq[0][s][n] + hq[1][s][n] + hq[2][s][n] + hq[3][s][n];
                h1[s][n] = v > 0.f ? v : expm1f(v);
            }
    }
    __syncthreads();

    {
        float a0[GS], a1[GS];
        #pragma unroll
        for (int s = 0; s < GS; ++s) { a0[s] = 0.f; a1[s] = 0.f; }
        const int i0 = kq * 32;
        #pragma unroll 8
        for (int i = i0; i < i0 + 32; ++i) {
            const float2 wv2 = *(const float2*)(W1t + (size_t)i * GATE_H + n0);
            #pragma unroll
            for (int s = 0; s < GS; ++s) {
                a0[s] = fmaf(h1[s][i], wv2.x, a0[s]);
                a1[s] = fmaf(h1[s][i], wv2.y, a1[s]);
            }
        }
        #pragma unroll
        for (int s = 0; s < GS; ++s) { hq[kq][s][n0] = a0[s]; hq[kq][s][n0 + 1] = a1[s]; }
    }
    __syncthreads();
    if (kq == 0) {
        #pragma unroll
        for (int s = 0; s < GS; ++s)
            #pragma unroll
            for (int j = 0; j < 2; ++j) {
                const int n = n0 + j;
                const float v = b1[n] + hq[0][s][n] + hq[1][s][n] + hq[2][s][n] + hq[3][s][n];
                h2[s][n] = v > 0.f ? v : expm1f(v);
            }
    }
    __syncthreads();

    if (t < GS * EXPERTS) {
        const int s = t >> 3, e = t & 7;
        float acc = b2[e];
        #pragma unroll 8
        for (int i = 0; i < GATE_H; ++i)
            acc = fmaf(h2[s][i], W2t[(size_t)i * EXPERTS + e], acc);
        red[s][e] = acc;
    }
    __syncthreads();
    if (t < GS) {
        float m = red[t][0];
        #pragma unroll
        for (int i = 1; i < EXPERTS; ++i) m = fmaxf(m, red[t][i]);
        float e[EXPERTS];
        float sum = 0.f;
        #pragma unroll
        for (int i = 0; i < EXPERTS; ++i) { e[i] = expf(red[t][i] - m); sum += e[i]; }
        const float inv = 1.f / sum;
        #pragma unroll
        for (int i = 0; i < EXPERTS; ++i)
            coeff[(size_t)(b4 + t) * EXPERTS + i] = e[i] * inv;
    }
}

// ---------------------------------------------------------------------------
// pack_all v2 (verified r11): weight packing (y<33) + activation packing
// (33<=y<49) + Lipschitz gate-weight row scaling (49<=y<58).
// ---------------------------------------------------------------------------
__global__ __launch_bounds__(256) void pack_all_kernel(
    const float* __restrict__ w0, const float* __restrict__ w1,
    const float* __restrict__ w2,
    const float* __restrict__ z, const float* __restrict__ c,
    u16* __restrict__ Bpk0, u16* __restrict__ Bpk1, u16* __restrict__ Bpk2,
    u16* __restrict__ Apk0, u16* __restrict__ Apk1, u16* __restrict__ Apk2,
    const float* __restrict__ gw0, const float* __restrict__ gc0,
    const float* __restrict__ gw1, const float* __restrict__ gc1,
    const float* __restrict__ gw2, const float* __restrict__ gc2,
    float* __restrict__ gW0t, float* __restrict__ gW1t, float* __restrict__ gW2t) {
    const int t = threadIdx.x, wv = t >> 6, l = t & 63;
    const int x = blockIdx.x, y = blockIdx.y;

    if (y < 33) {
        __shared__ float tile[4][16][33];
        const float* w; u16* Bpk; int IN, OUT, nblk;
        if (y < 16)      { w = w0; Bpk = Bpk0; IN = IN_DIM; OUT = HIDDEN;  nblk = y; }
        else if (y < 32) { w = w1; Bpk = Bpk1; IN = INTER;  OUT = HIDDEN;  nblk = y - 16; }
        else             { w = w2; Bpk = Bpk2; IN = INTER;  OUT = ACTIONS; nblk = 0; }
        const int NK = IN / 16;
        const int e = x, n0 = nblk * 32;
        const int col = l & 31, half = l >> 5;
        char* base = (char*)Bpk + ((size_t)(nblk * EXPERTS + e) * NK) * 1024;

        for (int jj = wv; jj < NK; jj += 4) {
            #pragma unroll
            for (int i = 0; i < 8; ++i) {
                const int r = i * 2 + half;
                float v = 0.f;
                if (n0 + col < OUT) v = w[((size_t)e * IN + jj * 16 + r) * OUT + n0 + col];
                tile[wv][r][col] = v;
            }
            short8 hh;
            #pragma unroll
            for (int i = 0; i < 8; ++i)
                hh[i] = (short)f2h(tile[wv][half * 8 + i][col]);
            *(short8*)(base + (size_t)jj * 1024 + l * 16) = hh;
        }
    } else if (y < 49) {
        constexpr int NK0 = 20, NK1 = 36;
        const int bblk = (y - 33) * 8 + x;
        const int r = l & 31, half = l >> 5;
        const int row = bblk * 32 + r;
        char* base0 = (char*)Apk0 + (size_t)bblk * NK0 * 1024;
        char* base1 = (char*)Apk1 + (size_t)bblk * NK1 * 1024;
        char* base2 = (char*)Apk2 + (size_t)bblk * NK1 * 1024;

        for (int jj = wv; jj < NK0; jj += 4) {
            const int k = jj * 16 + half * 8;
            const float* src = (k < LATENT) ? (z + (size_t)row * LATENT + k)
                                            : (c + (size_t)row * INPUT_SIZE + (k - LATENT));
            short8 hh;
            #pragma unroll
            for (int i = 0; i < 8; ++i) hh[i] = (short)f2h(src[i]);
            *(short8*)(base0 + (size_t)jj * 1024 + l * 16) = hh;
            if (jj < 4) {
                *(short8*)(base1 + (size_t)jj * 1024 + l * 16) = hh;
                *(short8*)(base2 + (size_t)jj * 1024 + l * 16) = hh;
            }
        }
    } else {
        const int row_g = (y - 49) * 32 + x * 4 + wv;
        if (row_g < 264) {
            const float* W; const float* cc; float* Wt; int cols, rows, row;
            if (row_g < 128)      { W = gw0; cc = gc0; Wt = gW0t; cols = IN_DIM; rows = GATE_H; row = row_g; }
            else if (row_g < 256) { W = gw1; cc = gc1; Wt = gW1t; cols = GATE_H; rows = GATE_H; row = row_g - 128; }
            else                  { W = gw2; cc = gc2; Wt = gW2t; cols = GATE_H; rows = EXPERTS; row = row_g - 256; }
            const float* w = W + (size_t)row * cols;
            float s = 0.f;
            for (int i = l; i < cols; i += 64) s += fabsf(w[i]);
            #pragma unroll
            for (int off = 32; off > 0; off >>= 1) s += __shfl_down(s, off, 64);
            s = __shfl(s, 0, 64);
            const float cv = cc[0];
            const float lipc = (cv > 0.f) ? (cv + log1pf(expf(-cv))) : log1pf(expf(cv));
            const float scale = fminf(lipc / s, 1.0f);
            for (int i = l; i < cols; i += 64)
                Wt[(size_t)i * rows + row] = w[i] * scale;
        }
    }
}

// ---------------------------------------------------------------------------
// Reduce split-K f16 partials + coeff-mixed bias + ELU -> packed next-A (f16)
// ---------------------------------------------------------------------------
template<int NPART>
__global__ __launch_bounds__(256) void reduce_pack_kernel(
    const u16* __restrict__ P16, const float* __restrict__ coeff,
    const float* __restrict__ bias, u16* __restrict__ ApkNext) {
    constexpr int NK = 36;
    __shared__ float biasS[EXPERTS][256];
    __shared__ float coeffS[32][9];
    const int t = threadIdx.x, wv = t >> 6, l = t & 63;
    const int bblk = blockIdx.x, ch = blockIdx.y;
    const int r = l & 31, half = l >> 5;
    const int row = bblk * 32 + r;

    for (int idx = t; idx < EXPERTS * 256; idx += 256)
        biasS[idx >> 8][idx & 255] = bias[(idx >> 8) * HIDDEN + ch * 256 + (idx & 255)];
    for (int idx = t; idx < 32 * 8; idx += 256)
        coeffS[idx >> 3][idx & 7] = coeff[(size_t)(bblk * 32 + (idx >> 3)) * 8 + (idx & 7)];
    __syncthreads();

    char* base = (char*)ApkNext + (size_t)bblk * NK * 1024;
    for (int jj = ch * 16 + wv; jj < ch * 16 + 16; jj += 4) {
        const int cb = jj * 16 + half * 8;
        float v[8];
        #pragma unroll
        for (int i = 0; i < 8; ++i) v[i] = 0.f;
        #pragma unroll
        for (int p = 0; p < NPART; ++p) {
            const short8 q = *(const short8*)(P16 + ((size_t)p * BATCH + row) * HIDDEN + cb);
            #pragma unroll
            for (int i = 0; i < 8; ++i) v[i] += h2f((u16)q[i]);
        }
        #pragma unroll
        for (int e = 0; e < EXPERTS; ++e) {
            const float cv = coeffS[r][e];
            #pragma unroll
            for (int i = 0; i < 8; ++i) v[i] = fmaf(cv, biasS[e][cb - ch * 256 + i], v[i]);
        }
        short8 hh;
        #pragma unroll
        for (int i = 0; i < 8; ++i) {
            const float hv = v[i] > 0.f ? v[i] : expm1f(v[i]);
            hh[i] = (short)f2h(hv);
        }
        *(short8*)(base + (size_t)(4 + jj) * 1024 + l * 16) = hh;
    }
}

// ---------------------------------------------------------------------------
// Final reduce: 8 f32 partials + coeff-mixed bias, OUT=12
// ---------------------------------------------------------------------------
__global__ __launch_bounds__(256) void reduce_out_kernel(
    const float* __restrict__ P2, const float* __restrict__ coeff,
    const float* __restrict__ b2, float* __restrict__ out) {
    const int t = threadIdx.x;
    const int bblk = blockIdx.x;
    for (int idx = t; idx < 32 * ACTIONS; idx += 256) {
        const int r = idx / ACTIONS, n = idx % ACTIONS;
        const int row = bblk * 32 + r;
        float s = 0.f;
        #pragma unroll
        for (int p = 0; p < 8; ++p) s += P2[((size_t)p * BATCH + row) * 32 + n];
        const float* cf = coeff + (size_t)row * 8;
        #pragma unroll
        for (int e = 0; e < 8; ++e) s = fmaf(cf[e], b2[e * ACTIONS + n], s);
        out[(size_t)row * ACTIONS + n] = s;
    }
}

// ---------------------------------------------------------------------------
// MoE GEMM v6 (verified r6-r11): single-plane f16, triple-buffered LDS A,
// 2-step-ahead prefetch, counted s_waitcnt vmcnt(12) + raw s_barrier.
// F16P selects f16 vs f32 partial stores.
// ---------------------------------------------------------------------------
template<int NK, int WN, int EPB, int OUTW, int GX, int GY, int GZ, bool F16P>
__global__ __launch_bounds__(128 * WN) void moe_gemm(
    const u16* __restrict__ Apk, const u16* __restrict__ Bpk,
    const float* __restrict__ coeff, void* __restrict__ Pout) {
    constexpr int TOT = NK / 4;
    constexpr int NWAVE = 2 * WN;
    constexpr int CPW = 16 / NWAVE;
    constexpr int CPX = GX / 8;

    __shared__ __align__(16) char As[3 * 16384];
    __shared__ float coeffT[EPB][128];

    const int t = threadIdx.x, wv = t >> 6, l = t & 63;
    const int wr = wv & 1, wc = wv >> 1;

    const int fid = blockIdx.x + GX * (blockIdx.y + GY * blockIdx.z);
    const int xcd = fid & 7, idx = fid >> 3;
    const int bx = xcd * CPX + (idx % CPX);
    const int yz = idx / CPX;
    const int by = yz % GY, bz = yz / GY;

    const int b0 = bx * 128;
    const int bblk0 = bx * 4;
    const int nblkg = by * WN + wc;
    const int part = bz;
    const int estart = part * EPB;

    for (int idx2 = t; idx2 < EPB * 128; idx2 += 128 * WN)
        coeffT[idx2 >> 7][idx2 & 127] =
            coeff[(size_t)(b0 + (idx2 & 127)) * EXPERTS + estart + (idx2 >> 7)];

    const char* Ab = (const char*)Apk;
    const char* Bbase[EPB];
    #pragma unroll
    for (int e = 0; e < EPB; ++e)
        Bbase[e] = (const char*)Bpk +
                   ((size_t)(nblkg * EXPERTS + estart + e) * NK) * 1024 + l * 16;

    f32x16 accE[EPB][2];
    #pragma unroll
    for (int e = 0; e < EPB; ++e) { accE[e][0] = (f32x16)0.f; accE[e][1] = (f32x16)0.f; }

    f16x8 breg[2][EPB][4];

    auto stageA = [&](int s) {
        char* dst = As + (s % 3) * 16384;
        #pragma unroll
        for (int q = 0; q < CPW; ++q) {
            const int cf = wv * CPW + q, bb = cf >> 2, kq = cf & 3;
            gload16(Ab + ((size_t)(bblk0 + bb) * NK + s * 4 + kq) * 1024 + l * 16,
                    dst + cf * 1024 + l * 16);
        }
    };

    __syncthreads();

    stageA(0);
    #pragma unroll
    for (int e = 0; e < EPB; ++e)
        #pragma unroll
        for (int q = 0; q < 4; ++q)
            breg[0][e][q] = *(const f16x8*)(Bbase[e] + (size_t)q * 1024);
    stageA(1);
    #pragma unroll
    for (int e = 0; e < EPB; ++e)
        #pragma unroll
        for (int q = 0; q < 4; ++q)
            breg[1][e][q] = *(const f16x8*)(Bbase[e] + (size_t)(4 + q) * 1024);

    #pragma unroll
    for (int s = 0; s < TOT; ++s) {
        if (s == TOT - 1) asm volatile("s_waitcnt vmcnt(0)" ::: "memory");
        else              asm volatile("s_waitcnt vmcnt(12)" ::: "memory");
        __builtin_amdgcn_sched_barrier(0);
        __builtin_amdgcn_s_barrier();
        __builtin_amdgcn_sched_barrier(0);

        if (s + 2 < TOT) stageA(s + 2);

        const char* buf = As + (s % 3) * 16384;
        f16x8 af0[4], af1[4];
        #pragma unroll
        for (int j = 0; j < 4; ++j) {
            af0[j] = *(const f16x8*)(buf + ((wr * 2 + 0) * 4 + j) * 1024 + l * 16);
            af1[j] = *(const f16x8*)(buf + ((wr * 2 + 1) * 4 + j) * 1024 + l * 16);
        }
        #pragma unroll
        for (int e = 0; e < EPB; ++e)
            #pragma unroll
            for (int j = 0; j < 4; ++j) {
                accE[e][0] = __builtin_amdgcn_mfma_f32_32x32x16_f16(af0[j], breg[s & 1][e][j], accE[e][0], 0, 0, 0);
                accE[e][1] = __builtin_amdgcn_mfma_f32_32x32x16_f16(af1[j], breg[s & 1][e][j], accE[e][1], 0, 0, 0);
            }
        if (s + 2 < TOT) {
            #pragma unroll
            for (int e = 0; e < EPB; ++e)
                #pragma unroll
                for (int q = 0; q < 4; ++q)
                    breg[s & 1][e][q] = *(const f16x8*)(Bbase[e] + (size_t)((s + 2) * 4 + q) * 1024);
        }
    }

    const int ncol = nblkg * 32 + (l & 31);
    #pragma unroll
    for (int m = 0; m < 2; ++m) {
        #pragma unroll
        for (int g = 0; g < 16; ++g) {
            const int rloc = (g & 3) + 8 * (g >> 2) + 4 * (l >> 5);
            const int row = wr * 64 + m * 32 + rloc;
            float v = 0.f;
            #pragma unroll
            for (int e = 0; e < EPB; ++e) v = fmaf(coeffT[e][row], accE[e][m][g], v);
            const size_t off = ((size_t)part * BATCH + b0 + row) * OUTW + ncol;
            if (F16P) ((u16*)Pout)[off] = f2h(v);
            else      ((float*)Pout)[off] = v;
        }
    }
}

// ---------------------------------------------------------------------------
extern "C" void kernel_launch(void* const* d_in, const int* in_sizes, int n_in,
                              void* d_out, int out_size, void* d_ws, size_t ws_size,
                              hipStream_t stream) {
    const float* z   = (const float*)d_in[0];
    const float* c   = (const float*)d_in[1];
    const float* w0  = (const float*)d_in[2];
    const float* b0  = (const float*)d_in[3];
    const float* w1  = (const float*)d_in[4];
    const float* b1  = (const float*)d_in[5];
    const float* w2  = (const float*)d_in[6];
    const float* b2  = (const float*)d_in[7];
    const float* gw0 = (const float*)d_in[8];
    const float* gb0 = (const float*)d_in[9];
    const float* gc0 = (const float*)d_in[10];
    const float* gw1 = (const float*)d_in[11];
    const float* gb1 = (const float*)d_in[12];
    const float* gc1 = (const float*)d_in[13];
    const float* gw2 = (const float*)d_in[14];
    const float* gb2 = (const float*)d_in[15];
    const float* gc2 = (const float*)d_in[16];
    float* out = (float*)d_out;

    char* p = (char*)d_ws;
    float* coeff = (float*)p;  p += (size_t)BATCH * EXPERTS * 4;
    float* gW0t  = (float*)p;  p += (size_t)GATE_H * IN_DIM * 4;
    float* gW1t  = (float*)p;  p += (size_t)GATE_H * GATE_H * 4;
    float* gW2t  = (float*)p;  p += (size_t)EXPERTS * GATE_H * 4;
    u16* Apk0 = (u16*)p;       p += (size_t)128 * 20 * 1024;
    u16* Apk1 = (u16*)p;       p += (size_t)128 * 36 * 1024;
    u16* Apk2 = (u16*)p;       p += (size_t)128 * 36 * 1024;
    u16* Bpk0 = (u16*)p;       p += (size_t)16 * 8 * 20 * 1024;
    u16* Bpk1 = (u16*)p;       p += (size_t)16 * 8 * 36 * 1024;
    u16* Bpk2 = (u16*)p;       p += (size_t)8 * 36 * 1024;
    u16* P16  = (u16*)p;       p += (size_t)4 * BATCH * HIDDEN * 2;   // 16 MB
    float* P32 = (float*)P16;  // L2 path reuses region as f32 (4 MB)

    // fused packing + gate-weight scaling (one launch)
    pack_all_kernel<<<dim3(8, 58), 256, 0, stream>>>(
        w0, w1, w2, z, c, Bpk0, Bpk1, Bpk2, Apk0, Apk1, Apk2,
        gw0, gc0, gw1, gc1, gw2, gc2, gW0t, gW1t, gW2t);

    // gate MLP
    gate_forward_v4<<<BATCH / GS, 256, 0, stream>>>(z, c, gW0t, gb0, gW1t, gb1,
                                                    gW2t, gb2, coeff);

    // layer 0: NK=20, 5 steps, f16 partials
    moe_gemm<20, 2, 2, HIDDEN, 32, 8, 4, true><<<dim3(32, 8, 4), 256, 0, stream>>>(
        Apk0, Bpk0, coeff, P16);
    reduce_pack_kernel<4><<<dim3(128, 2), 256, 0, stream>>>(P16, coeff, b0, Apk1);

    // layer 1: NK=36, 9 steps, f16 partials
    moe_gemm<36, 2, 2, HIDDEN, 32, 8, 4, true><<<dim3(32, 8, 4), 256, 0, stream>>>(
        Apk1, Bpk1, coeff, P16);
    reduce_pack_kernel<4><<<dim3(128, 2), 256, 0, stream>>>(P16, coeff, b1, Apk2);

    // layer 2: split-K 8 over experts, OUT padded 32, f32 partials
    moe_gemm<36, 1, 1, 32, 32, 1, 8, false><<<dim3(32, 1, 8), 128, 0, stream>>>(
        Apk2, Bpk2, coeff, P32);
    reduce_out_kernel<<<128, 256, 0, stream>>>(P32, coeff, b2, out);
}